// Round 1
// baseline (1349.434 us; speedup 1.0000x reference)
//
#include <hip/hip_runtime.h>
#include <math.h>

#define BB 32
#define NN 512
#define MM 64
#define DD 128
#define TILE 64
#define NTILES (NN / TILE)
#define EPSF 1e-15f
#define PAD 68

struct SMem {
  float ST[DD][PAD];     // S^T (ST[d][m]), padded for float4-aligned, low-conflict reads
  float VL[TILE][DD];    // V chunk (row-major, contiguous)
  float Cb[TILE][PAD];   // normalized cosine tile C[n][m]
  float Pb[TILE][PAD];   // e (row pass) then p (column pass)
  float GS[MM][PAD];     // Gram of S[j]
  float ns_l[MM];
  float nv_l[TILE];
  float cmax[MM], csum[MM], ssnum[MM], fres[MM];
  float red[8][MM];
  float red2[8][MM];
  float svred[8];
};

extern "C" __global__ void __launch_bounds__(512, 2)
mv_fused(const float* __restrict__ Vg, const float* __restrict__ Sg,
         float* __restrict__ out)
{
  extern __shared__ char smraw[];
  SMem& sm = *reinterpret_cast<SMem*>(smraw);

  const int t    = threadIdx.x;
  const int lane = t & 63;
  const int wave = t >> 6;
  const int bid  = blockIdx.x;
  const int bi   = bid >> 5;
  const int bj   = bid & 31;

  const float* Vi = Vg + (size_t)bi * NN * DD;
  const float* Sj = Sg + (size_t)bj * MM * DD;

  // ---- load S^T (transposed into LDS) + ns ----
  #pragma unroll
  for (int k = 0; k < 4; ++k) {
    const int f  = t + 512 * k;          // float4 index, 2048 total
    const int m  = f >> 5;               // uniform across each 32-lane half
    const int d4 = f & 31;
    const float4 v = reinterpret_cast<const float4*>(Sj)[f];
    sm.ST[d4*4+0][m] = v.x;
    sm.ST[d4*4+1][m] = v.y;
    sm.ST[d4*4+2][m] = v.z;
    sm.ST[d4*4+3][m] = v.w;
    float s = v.x*v.x + v.y*v.y + v.z*v.z + v.w*v.w;
    #pragma unroll
    for (int msk = 16; msk >= 1; msk >>= 1) s += __shfl_xor(s, msk, 64);
    if ((lane & 31) == 0) sm.ns_l[m] = sqrtf(s);
  }
  if (t < MM) { sm.cmax[t] = -1e30f; sm.csum[t] = 0.f; sm.ssnum[t] = 0.f; }
  __syncthreads();

  // ---- Gram matrix GS[m][m2] = S[m]·S[m2] ----
  {
    const int gm  = t >> 3;
    const int gm2 = (t & 7) * 8;
    float acc8[8] = {0,0,0,0,0,0,0,0};
    for (int d = 0; d < DD; ++d) {
      const float a = sm.ST[d][gm];
      float b_[8];
      *reinterpret_cast<float4*>(&b_[0]) = *reinterpret_cast<const float4*>(&sm.ST[d][gm2]);
      *reinterpret_cast<float4*>(&b_[4]) = *reinterpret_cast<const float4*>(&sm.ST[d][gm2+4]);
      #pragma unroll
      for (int q = 0; q < 8; ++q) acc8[q] += a * b_[q];
    }
    *reinterpret_cast<float4*>(&sm.GS[gm][gm2])   = *reinterpret_cast<float4*>(&acc8[0]);
    *reinterpret_cast<float4*>(&sm.GS[gm][gm2+4]) = *reinterpret_cast<float4*>(&acc8[4]);
  }

  float bt[16];                 // Bt accumulator: this thread owns (m=lane, d = wave*16..+15)
  #pragma unroll
  for (int k = 0; k < 16; ++k) bt[k] = 0.f;
  float svacc = 0.f;

  for (int tt = 0; tt < NTILES; ++tt) {
    __syncthreads();            // prior tile's readers done; GS ready on first iter

    // ---- load V chunk + row norms ----
    {
      const float* Vc = Vi + tt * TILE * DD;
      #pragma unroll
      for (int k = 0; k < 4; ++k) {
        const int f = t + 512 * k;
        const float4 v = reinterpret_cast<const float4*>(Vc)[f];
        reinterpret_cast<float4*>(&sm.VL[0][0])[f] = v;
        float s = v.x*v.x + v.y*v.y + v.z*v.z + v.w*v.w;
        #pragma unroll
        for (int msk = 16; msk >= 1; msk >>= 1) s += __shfl_xor(s, msk, 64);
        if ((lane & 31) == 0) sm.nv_l[f >> 5] = sqrtf(s);
      }
    }
    __syncthreads();

    // ---- dot: C[r][m] for 64 rows x 64 cols ----
    {
      const int lr = lane >> 4;       // 0..3
      const int lm = lane & 15;       // 0..15 -> m = 4*lm..+3
      const int r0 = wave * 8 + lr;
      const int r1 = r0 + 4;
      float acc0[4] = {0,0,0,0}, acc1[4] = {0,0,0,0};
      for (int d4 = 0; d4 < 32; ++d4) {
        float va_[4], vb_[4];
        *reinterpret_cast<float4*>(va_) = *reinterpret_cast<const float4*>(&sm.VL[r0][d4*4]);
        *reinterpret_cast<float4*>(vb_) = *reinterpret_cast<const float4*>(&sm.VL[r1][d4*4]);
        #pragma unroll
        for (int q = 0; q < 4; ++q) {
          float s_[4];
          *reinterpret_cast<float4*>(s_) = *reinterpret_cast<const float4*>(&sm.ST[d4*4+q][lm*4]);
          #pragma unroll
          for (int mq = 0; mq < 4; ++mq) {
            acc0[mq] += va_[q] * s_[mq];
            acc1[mq] += vb_[q] * s_[mq];
          }
        }
      }
      const float nv0 = sm.nv_l[r0], nv1 = sm.nv_l[r1];
      float c0[4], c1[4];
      #pragma unroll
      for (int mq = 0; mq < 4; ++mq) {
        const float nsm = sm.ns_l[lm*4+mq];
        c0[mq] = acc0[mq] / (nv0 * nsm + EPSF);
        c1[mq] = acc1[mq] / (nv1 * nsm + EPSF);
      }
      *reinterpret_cast<float4*>(&sm.Cb[r0][lm*4]) = *reinterpret_cast<float4*>(c0);
      *reinterpret_cast<float4*>(&sm.Cb[r1][lm*4]) = *reinterpret_cast<float4*>(c1);
    }
    __syncthreads();

    // ---- row pass part 1: e = exp(C - rowmax), row sums, sv numerator ----
    const int rn  = t >> 3;           // row 0..63
    const int sub = t & 7;            // m-slice: m = sub*8..+7
    float e_[8];
    float esum, svr, nvn;
    {
      float cv[8];
      *reinterpret_cast<float4*>(&cv[0]) = *reinterpret_cast<const float4*>(&sm.Cb[rn][sub*8]);
      *reinterpret_cast<float4*>(&cv[4]) = *reinterpret_cast<const float4*>(&sm.Cb[rn][sub*8+4]);
      float rmax = cv[0];
      #pragma unroll
      for (int q = 1; q < 8; ++q) rmax = fmaxf(rmax, cv[q]);
      #pragma unroll
      for (int msk = 4; msk >= 1; msk >>= 1) rmax = fmaxf(rmax, __shfl_xor(rmax, msk, 64));
      nvn  = sm.nv_l[rn];
      esum = 0.f; svr = 0.f;
      #pragma unroll
      for (int q = 0; q < 8; ++q) {
        const float ev = __expf(cv[q] - rmax);
        e_[q] = ev;
        esum += ev;
        const float nsm = sm.ns_l[sub*8+q];
        svr += ev * (cv[q] * (nvn * nsm + EPSF));   // e * rawdot
      }
      #pragma unroll
      for (int msk = 4; msk >= 1; msk >>= 1) {
        esum += __shfl_xor(esum, msk, 64);
        svr  += __shfl_xor(svr,  msk, 64);
      }
      *reinterpret_cast<float4*>(&sm.Pb[rn][sub*8])   = *reinterpret_cast<float4*>(&e_[0]);
      *reinterpret_cast<float4*>(&sm.Pb[rn][sub*8+4]) = *reinterpret_cast<float4*>(&e_[4]);
    }
    __syncthreads();

    // ---- row pass part 2: quadratic form e^T GS e -> ||A|| ----
    {
      float qf = 0.f;
      for (int m = 0; m < MM; ++m) {
        const float em = sm.Pb[rn][m];
        float g_[8];
        *reinterpret_cast<float4*>(&g_[0]) = *reinterpret_cast<const float4*>(&sm.GS[m][sub*8]);
        *reinterpret_cast<float4*>(&g_[4]) = *reinterpret_cast<const float4*>(&sm.GS[m][sub*8+4]);
        float inner = 0.f;
        #pragma unroll
        for (int q = 0; q < 8; ++q) inner += e_[q] * g_[q];
        qf += em * inner;
      }
      #pragma unroll
      for (int msk = 4; msk >= 1; msk >>= 1) qf += __shfl_xor(qf, msk, 64);
      // sv = (svr/esum) / (nvn*sqrt(qf)/esum + EPS) = svr / (nvn*sqrt(qf) + EPS*esum)
      if (sub == 0) svacc += svr / (nvn * sqrtf(qf) + EPSF * esum);
    }
    __syncthreads();

    // ---- column pass (online softmax over n) ----
    {
      const int m  = lane;
      const int rg = wave;
      float cl[8];
      float cm = -1e30f;
      #pragma unroll
      for (int q = 0; q < 8; ++q) { cl[q] = sm.Cb[rg*8+q][m]; cm = fmaxf(cm, cl[q]); }
      sm.red[rg][m] = cm;
      __syncthreads();
      if (t < MM) {
        float tm = sm.red[0][t];
        #pragma unroll
        for (int g = 1; g < 8; ++g) tm = fmaxf(tm, sm.red[g][t]);
        const float om = sm.cmax[t];
        const float nm = fmaxf(om, tm);
        const float f  = __expf(om - nm);   // first tile: exp(-1e30-nm) == 0
        sm.fres[t]   = f;
        sm.cmax[t]   = nm;
        sm.csum[t]  *= f;
        sm.ssnum[t] *= f;
      }
      __syncthreads();
      const float nm  = sm.cmax[m];
      const float nsm = sm.ns_l[m];
      const float fr  = sm.fres[m];
      #pragma unroll
      for (int k = 0; k < 16; ++k) bt[k] *= fr;
      float psum = 0.f, ssp = 0.f;
      #pragma unroll
      for (int q = 0; q < 8; ++q) {
        const int n = rg*8 + q;
        const float p = __expf(cl[q] - nm);
        psum += p;
        ssp  += p * (cl[q] * (sm.nv_l[n] * nsm + EPSF));  // p * rawdot
        sm.Pb[n][m] = p;
      }
      sm.red[rg][m]  = psum;
      sm.red2[rg][m] = ssp;
      __syncthreads();
      if (t < MM) {
        float s1 = sm.red[0][t], s2 = sm.red2[0][t];
        #pragma unroll
        for (int g = 1; g < 8; ++g) { s1 += sm.red[g][t]; s2 += sm.red2[g][t]; }
        sm.csum[t]  += s1;
        sm.ssnum[t] += s2;
      }
      // bt accumulation: reads Pb (written before last barrier) + VL (stable this tile)
      const int d0 = wave * 16;
      for (int n = 0; n < TILE; ++n) {
        const float p = sm.Pb[n][m];
        float v_[16];
        #pragma unroll
        for (int k4 = 0; k4 < 4; ++k4)
          *reinterpret_cast<float4*>(&v_[k4*4]) =
              *reinterpret_cast<const float4*>(&sm.VL[n][d0 + k4*4]);
        #pragma unroll
        for (int k = 0; k < 16; ++k) bt[k] += p * v_[k];
      }
    }
  }

  // ---- epilogue ----
  __syncthreads();
  {
    float btq = 0.f;
    #pragma unroll
    for (int k = 0; k < 16; ++k) btq += bt[k] * bt[k];
    sm.red[wave][lane] = btq;
  }
  __syncthreads();
  if (t < MM) {
    float q = sm.red[0][t];
    #pragma unroll
    for (int g = 1; g < 8; ++g) q += sm.red[g][t];
    // ss = (ssnum/csum) / (ns*sqrt(q)/csum + EPS) = ssnum / (ns*sqrt(q) + EPS*csum)
    float ss = sm.ssnum[t] / (sm.ns_l[t] * sqrtf(q) + EPSF * sm.csum[t]);
    #pragma unroll
    for (int msk = 32; msk >= 1; msk >>= 1) ss += __shfl_xor(ss, msk, 64);
    if (t == 0) out[BB*BB + bj*BB + bi] = ss * (1.0f / MM);  // transposed output
  }
  {
    float sv = svacc;
    #pragma unroll
    for (int msk = 32; msk >= 1; msk >>= 1) sv += __shfl_xor(sv, msk, 64);
    if (lane == 0) sm.svred[wave] = sv;
  }
  __syncthreads();
  if (t == 0) {
    float s = 0.f;
    #pragma unroll
    for (int w = 0; w < 8; ++w) s += sm.svred[w];
    out[bi*BB + bj] = s * (1.0f / NN);
  }
}

extern "C" void kernel_launch(void* const* d_in, const int* in_sizes, int n_in,
                              void* d_out, int out_size, void* d_ws, size_t ws_size,
                              hipStream_t stream) {
  const float* V = (const float*)d_in[0];   // [32, 512, 128] f32
  const float* S = (const float*)d_in[1];   // [32, 64, 128] f32
  float* out = (float*)d_out;               // [2048] f32: out1 [32,32] then out2 [32,32]

  static_assert(sizeof(SMem) <= 160 * 1024, "LDS budget");
  hipFuncSetAttribute(reinterpret_cast<const void*>(mv_fused),
                      hipFuncAttributeMaxDynamicSharedMemorySize,
                      (int)sizeof(SMem));
  mv_fused<<<dim3(BB * BB), dim3(512), sizeof(SMem), stream>>>(V, S, out);
}

// Round 3
// 195.364 us; speedup vs baseline: 6.9073x; 6.9073x over previous
//
#include <hip/hip_runtime.h>
#include <math.h>

#define BB 32
#define NN 512
#define MM 64
#define DD 128
#define TILE 64
#define NTILES 8
#define EPSF 1e-15f

typedef __attribute__((ext_vector_type(8))) short s8v;      // 8 bf16 (4 VGPR) MFMA A/B frag
typedef __attribute__((ext_vector_type(4))) float f4v;      // MFMA C/D frag
typedef __attribute__((ext_vector_type(4))) unsigned short u4v;
typedef __attribute__((ext_vector_type(8))) unsigned short u8v;

#define MFMA(a, b, c) __builtin_amdgcn_mfma_f32_16x16x32_bf16((a), (b), (c), 0, 0, 0)

__device__ inline unsigned short f2b(float f) {           // f32 -> bf16 RNE
  unsigned int u = __float_as_uint(f);
  return (unsigned short)((u + 0x7fffu + ((u >> 16) & 1u)) >> 16);
}
__device__ inline float b2f(unsigned short h) {
  return __uint_as_float(((unsigned int)h) << 16);
}
// XOR-swizzled element indices (bf16): byte ^= (row&7)<<4  <=>  elem ^= (row&7)<<3
__device__ inline int idxV(int r, int k)  { return r * 128 + (k ^ ((r & 7) << 3)); } // 128-col
__device__ inline int idx64(int r, int k) { return r * 64  + (k ^ ((r & 7) << 3)); } // 64-col

struct __align__(16) SMem {
  unsigned short VA[64 * 128];  // union-by-reuse: Vb[64][128] (dot A), then VTb[128][64] (bt B)
  unsigned short Sb[64 * 128];  // S tile bf16 [64][128] (dot B / GS A+B)
  unsigned short Gb[64 * 64];   // Gram(S) bf16 [64][64] (quad B; symmetric)
  unsigned short EP[64 * 64];   // reuse: Eb (row-pass e, quad A) then PTb (p^T, bt A)
  float Cb[64][68];             // normalized cosine tile, f32
  float ns_l[64], nv_l[64];
  float cmax[64], csum[64], ssnum[64], fres[64];
  float svr_s[64], esum_s[64];
  float qfp[8][16];
  float red[8][64], red2[8][64];
};

extern "C" __global__ void __launch_bounds__(512, 4)
mv_mfma(const float* __restrict__ Vg, const float* __restrict__ Sg,
        float* __restrict__ out)
{
  extern __shared__ char smraw[];
  SMem& sm = *reinterpret_cast<SMem*>(smraw);

  const int t    = threadIdx.x;
  const int lane = t & 63;
  const int w    = t >> 6;
  const int l15  = lane & 15;
  const int g    = lane >> 4;          // 0..3
  const int bid  = blockIdx.x;
  const int bi   = bid >> 5;
  const int bj   = bid & 31;

  const float* Vi = Vg + (size_t)bi * NN * DD;
  const float* Sj = Sg + (size_t)bj * MM * DD;

  const int nb  = w >> 1;              // 16-row block (M side) for dot/GS/quad
  const int mb0 = (w & 1) * 2;         // first of two 16-col blocks (N side)
  const int cB0 = mb0 * 16 + l15;      // B-frag col, tile 0
  const int cB1 = cB0 + 16;            // B-frag col, tile 1

  // ---- stage S (bf16, swizzled) + ns, init online-softmax state ----
  #pragma unroll
  for (int k = 0; k < 4; ++k) {
    const int f = t + 512 * k;         // 2048 float4s
    const int m = f >> 5, c = f & 31;
    const float4 v = reinterpret_cast<const float4*>(Sj)[f];
    u4v pk = { f2b(v.x), f2b(v.y), f2b(v.z), f2b(v.w) };
    *reinterpret_cast<u4v*>(&sm.Sb[idxV(m, c * 4)]) = pk;
    float s = v.x * v.x + v.y * v.y + v.z * v.z + v.w * v.w;
    #pragma unroll
    for (int msk = 16; msk >= 1; msk >>= 1) s += __shfl_xor(s, msk, 64);
    if ((lane & 31) == 0) sm.ns_l[m] = sqrtf(s);
  }
  if (t < 64) { sm.cmax[t] = -1e30f; sm.csum[t] = 0.f; sm.ssnum[t] = 0.f; }
  __syncthreads();

  // ---- Gram(S) via MFMA: GS[m][m2] = S[m].S[m2] ----
  {
    f4v g0 = {0.f, 0.f, 0.f, 0.f}, g1 = {0.f, 0.f, 0.f, 0.f};
    #pragma unroll
    for (int ks = 0; ks < 4; ++ks) {
      s8v a  = *reinterpret_cast<const s8v*>(&sm.Sb[idxV(nb * 16 + l15, ks * 32 + g * 8)]);
      s8v b0 = *reinterpret_cast<const s8v*>(&sm.Sb[idxV(cB0,          ks * 32 + g * 8)]);
      s8v b1 = *reinterpret_cast<const s8v*>(&sm.Sb[idxV(cB1,          ks * 32 + g * 8)]);
      g0 = MFMA(a, b0, g0);
      g1 = MFMA(a, b1, g1);
    }
    #pragma unroll
    for (int q = 0; q < 4; ++q) {
      const int row = nb * 16 + g * 4 + q;
      sm.Gb[idx64(row, cB0)] = f2b(g0[q]);
      sm.Gb[idx64(row, cB1)] = f2b(g1[q]);
    }
  }
  // (Gb consumed first inside the tile loop, after >=2 barriers)

  f4v bt4[4] = {{0.f,0.f,0.f,0.f},{0.f,0.f,0.f,0.f},{0.f,0.f,0.f,0.f},{0.f,0.f,0.f,0.f}};
  float svacc = 0.f;

  const float* Vc = Vi;  // set per tile below
  for (int tt = 0; tt < NTILES; ++tt) {
    __syncthreads();                   // prev bt readers (VA/EP) done
    Vc = Vi + (size_t)tt * TILE * DD;

    // ---- stage V tile (bf16 swizzled) + row norms ----
    #pragma unroll
    for (int k = 0; k < 4; ++k) {
      const int f = t + 512 * k;
      const int n = f >> 5, c = f & 31;
      const float4 v = reinterpret_cast<const float4*>(Vc)[f];
      u4v pk = { f2b(v.x), f2b(v.y), f2b(v.z), f2b(v.w) };
      *reinterpret_cast<u4v*>(&sm.VA[idxV(n, c * 4)]) = pk;
      float s = v.x * v.x + v.y * v.y + v.z * v.z + v.w * v.w;
      #pragma unroll
      for (int msk = 16; msk >= 1; msk >>= 1) s += __shfl_xor(s, msk, 64);
      if ((lane & 31) == 0) sm.nv_l[n] = sqrtf(s);
    }
    __syncthreads();

    // ---- dot: C = V.S^T via MFMA, normalize, store f32 to Cb ----
    {
      f4v a0 = {0.f,0.f,0.f,0.f}, a1 = {0.f,0.f,0.f,0.f};
      const int ar = nb * 16 + l15;
      #pragma unroll
      for (int ks = 0; ks < 4; ++ks) {
        s8v av = *reinterpret_cast<const s8v*>(&sm.VA[idxV(ar,  ks * 32 + g * 8)]);
        s8v b0 = *reinterpret_cast<const s8v*>(&sm.Sb[idxV(cB0, ks * 32 + g * 8)]);
        s8v b1 = *reinterpret_cast<const s8v*>(&sm.Sb[idxV(cB1, ks * 32 + g * 8)]);
        a0 = MFMA(av, b0, a0);
        a1 = MFMA(av, b1, a1);
      }
      const float ns0 = sm.ns_l[cB0], ns1 = sm.ns_l[cB1];
      #pragma unroll
      for (int q = 0; q < 4; ++q) {
        const int row = nb * 16 + g * 4 + q;
        const float nv_ = sm.nv_l[row];
        sm.Cb[row][cB0] = a0[q] / (nv_ * ns0 + EPSF);
        sm.Cb[row][cB1] = a1[q] / (nv_ * ns1 + EPSF);
      }
    }
    __syncthreads();

    // ---- row pass: e = exp(C - rowmax), esum, sv numerator; Eb (bf16) ----
    const int rn = t >> 3, sub = t & 7;
    {
      float cv[8];
      *reinterpret_cast<float4*>(&cv[0]) = *reinterpret_cast<const float4*>(&sm.Cb[rn][sub * 8]);
      *reinterpret_cast<float4*>(&cv[4]) = *reinterpret_cast<const float4*>(&sm.Cb[rn][sub * 8 + 4]);
      float rmax = cv[0];
      #pragma unroll
      for (int q = 1; q < 8; ++q) rmax = fmaxf(rmax, cv[q]);
      #pragma unroll
      for (int msk = 4; msk >= 1; msk >>= 1) rmax = fmaxf(rmax, __shfl_xor(rmax, msk, 64));
      const float nvn = sm.nv_l[rn];
      float esum = 0.f, svr = 0.f;
      u8v ev;
      #pragma unroll
      for (int q = 0; q < 8; ++q) {
        const float e = __expf(cv[q] - rmax);
        ev[q] = f2b(e);
        esum += e;
        svr += e * (cv[q] * (nvn * sm.ns_l[sub * 8 + q] + EPSF));  // e * rawdot
      }
      #pragma unroll
      for (int msk = 4; msk >= 1; msk >>= 1) {
        esum += __shfl_xor(esum, msk, 64);
        svr  += __shfl_xor(svr,  msk, 64);
      }
      *reinterpret_cast<u8v*>(&sm.EP[idx64(rn, sub * 8)]) = ev;
      if (sub == 0) { sm.svr_s[rn] = svr; sm.esum_s[rn] = esum; }
    }
    __syncthreads();

    // ---- quad form F = E.GS via MFMA (qf = e^T GS e) + VT staging overlap ----
    {
      const int d   = (w & 1) * 64 + lane;     // column of V this thread transposes
      const int n0v = (w >> 1) * 16;
      float vv[16];
      #pragma unroll
      for (int q = 0; q < 16; ++q) vv[q] = Vc[(size_t)(n0v + q) * DD + d];  // coalesced

      f4v fa0 = {0.f,0.f,0.f,0.f}, fa1 = {0.f,0.f,0.f,0.f};
      #pragma unroll
      for (int ks = 0; ks < 2; ++ks) {
        s8v ea  = *reinterpret_cast<const s8v*>(&sm.EP[idx64(nb * 16 + l15, ks * 32 + g * 8)]);
        s8v gb0 = *reinterpret_cast<const s8v*>(&sm.Gb[idx64(cB0,           ks * 32 + g * 8)]);
        s8v gb1 = *reinterpret_cast<const s8v*>(&sm.Gb[idx64(cB1,           ks * 32 + g * 8)]);
        fa0 = MFMA(ea, gb0, fa0);
        fa1 = MFMA(ea, gb1, fa1);
      }
      float qp[4];
      #pragma unroll
      for (int q = 0; q < 4; ++q) {
        const int row = nb * 16 + g * 4 + q;
        qp[q] = b2f(sm.EP[idx64(row, cB0)]) * fa0[q]
              + b2f(sm.EP[idx64(row, cB1)]) * fa1[q];
      }
      #pragma unroll
      for (int msk = 8; msk >= 1; msk >>= 1) {
        #pragma unroll
        for (int q = 0; q < 4; ++q) qp[q] += __shfl_xor(qp[q], msk, 64);
      }
      if (l15 == 0) {
        #pragma unroll
        for (int q = 0; q < 4; ++q) sm.qfp[w][g * 4 + q] = qp[q];
      }
      // write V^T bf16 into VA (Vb is dead after the dot phase)
      u8v p0, p1;
      #pragma unroll
      for (int q = 0; q < 8; ++q) { p0[q] = f2b(vv[q]); p1[q] = f2b(vv[q + 8]); }
      *reinterpret_cast<u8v*>(&sm.VA[idx64(d, n0v)])     = p0;
      *reinterpret_cast<u8v*>(&sm.VA[idx64(d, n0v + 8)]) = p1;
    }
    __syncthreads();

    // ---- sv update + column pass (online softmax over n) ----
    if (t < 64) {
      const float qf = sm.qfp[2 * (t >> 4)][t & 15] + sm.qfp[2 * (t >> 4) + 1][t & 15];
      svacc += sm.svr_s[t] / (sm.nv_l[t] * sqrtf(qf) + EPSF * sm.esum_s[t]);
    }
    const int m = lane, rg = w;
    float cl[8];
    {
      float cm = -1e30f;
      #pragma unroll
      for (int q = 0; q < 8; ++q) { cl[q] = sm.Cb[rg * 8 + q][m]; cm = fmaxf(cm, cl[q]); }
      sm.red[rg][m] = cm;
    }
    __syncthreads();
    if (t < 64) {
      float tm = sm.red[0][t];
      #pragma unroll
      for (int g2 = 1; g2 < 8; ++g2) tm = fmaxf(tm, sm.red[g2][t]);
      const float om = sm.cmax[t];
      const float nm = fmaxf(om, tm);
      const float f  = __expf(om - nm);
      sm.fres[t] = f; sm.cmax[t] = nm; sm.csum[t] *= f; sm.ssnum[t] *= f;
    }
    __syncthreads();
    {
      const float nm  = sm.cmax[m];
      const float nsm = sm.ns_l[m];
      float psum = 0.f, ssp = 0.f;
      u8v pv;
      #pragma unroll
      for (int q = 0; q < 8; ++q) {
        const int n = rg * 8 + q;
        const float p = __expf(cl[q] - nm);
        psum += p;
        ssp  += p * (cl[q] * (sm.nv_l[n] * nsm + EPSF));  // p * rawdot
        pv[q] = f2b(p);
      }
      *reinterpret_cast<u8v*>(&sm.EP[idx64(m, rg * 8)]) = pv;  // P^T bf16 (Eb is dead)
      sm.red[rg][m] = psum; sm.red2[rg][m] = ssp;
    }
    __syncthreads();
    if (t < 64) {
      float s1 = sm.red[0][t], s2 = sm.red2[0][t];
      #pragma unroll
      for (int g2 = 1; g2 < 8; ++g2) { s1 += sm.red[g2][t]; s2 += sm.red2[g2][t]; }
      sm.csum[t] += s1; sm.ssnum[t] += s2;
    }
    // ---- bt += P^T.V via MFMA (rescale acc by fres first) ----
    {
      const int mbB = w >> 1, db0 = (w & 1) * 4;
      const int arow = mbB * 16 + l15;
      float fq[4];
      #pragma unroll
      for (int q = 0; q < 4; ++q) fq[q] = sm.fres[mbB * 16 + g * 4 + q];
      #pragma unroll
      for (int dt = 0; dt < 4; ++dt) {
        #pragma unroll
        for (int q = 0; q < 4; ++q) bt4[dt][q] *= fq[q];
      }
      #pragma unroll
      for (int ks = 0; ks < 2; ++ks) {
        s8v pa = *reinterpret_cast<const s8v*>(&sm.EP[idx64(arow, ks * 32 + g * 8)]);
        #pragma unroll
        for (int dt = 0; dt < 4; ++dt) {
          s8v vb = *reinterpret_cast<const s8v*>(&sm.VA[idx64((db0 + dt) * 16 + l15, ks * 32 + g * 8)]);
          bt4[dt] = MFMA(pa, vb, bt4[dt]);
        }
      }
    }
  }

  // ---- epilogue: ||bt|| per m, final scores ----
  __syncthreads();
  {
    float bq[4];
    #pragma unroll
    for (int q = 0; q < 4; ++q)
      bq[q] = bt4[0][q] * bt4[0][q] + bt4[1][q] * bt4[1][q]
            + bt4[2][q] * bt4[2][q] + bt4[3][q] * bt4[3][q];
    #pragma unroll
    for (int msk = 8; msk >= 1; msk >>= 1) {
      #pragma unroll
      for (int q = 0; q < 4; ++q) bq[q] += __shfl_xor(bq[q], msk, 64);
    }
    if (l15 == 0) {
      #pragma unroll
      for (int q = 0; q < 4; ++q) sm.red[w][g * 4 + q] = bq[q];
    }
  }
  __syncthreads();
  if (w == 0) {
    const float btq = sm.red[2 * (lane >> 4)][lane & 15] + sm.red[2 * (lane >> 4) + 1][lane & 15];
    float ssv = sm.ssnum[lane] / (sm.ns_l[lane] * sqrtf(btq) + EPSF * sm.csum[lane]);
    float svv = svacc;
    #pragma unroll
    for (int msk = 32; msk >= 1; msk >>= 1) {
      ssv += __shfl_xor(ssv, msk, 64);
      svv += __shfl_xor(svv, msk, 64);
    }
    if (lane == 0) {
      out[bi * BB + bj]           = svv * (1.0f / NN);
      out[BB * BB + bj * BB + bi] = ssv * (1.0f / MM);  // transposed output
    }
  }
}

extern "C" void kernel_launch(void* const* d_in, const int* in_sizes, int n_in,
                              void* d_out, int out_size, void* d_ws, size_t ws_size,
                              hipStream_t stream) {
  const float* V = (const float*)d_in[0];   // [32, 512, 128] f32
  const float* S = (const float*)d_in[1];   // [32, 64, 128] f32
  float* out = (float*)d_out;               // [2048] f32

  static_assert(sizeof(SMem) <= 80 * 1024, "need 2 blocks/CU");
  hipFuncSetAttribute(reinterpret_cast<const void*>(mv_mfma),
                      hipFuncAttributeMaxDynamicSharedMemorySize,
                      (int)sizeof(SMem));
  mv_mfma<<<dim3(BB * BB), dim3(512), sizeof(SMem), stream>>>(V, S, out);
}

// Round 4
// 178.541 us; speedup vs baseline: 7.5581x; 1.0942x over previous
//
#include <hip/hip_runtime.h>
#include <hip/hip_bf16.h>
#include <math.h>

#define BB 32
#define NN 512
#define MM 64
#define DD 128
#define TILE 64
#define NTILES 8
#define EPSF 1e-15f

typedef __attribute__((ext_vector_type(8))) short s8v;      // 8 bf16 MFMA A/B frag
typedef __attribute__((ext_vector_type(4))) float f4v;      // MFMA C/D frag
typedef __attribute__((ext_vector_type(4))) unsigned short u4v;
typedef __attribute__((ext_vector_type(8))) unsigned short u8v;

#define MFMA(a, b, c) __builtin_amdgcn_mfma_f32_16x16x32_bf16((a), (b), (c), 0, 0, 0)

__device__ inline unsigned short f2b(float f) {   // native RNE cvt (pairs into v_cvt_pk_bf16_f32)
  union { __hip_bfloat16 b; unsigned short u; } cv;
  cv.b = __float2bfloat16(f);
  return cv.u;
}

// XOR-swizzle (bf16 elems): elem ^= (row&7)<<3 — transparent for 8-aligned vector access
__device__ inline int idxV(int r, int k)  { return r * 128 + (k ^ ((r & 7) << 3)); } // 128-col
__device__ inline int idx64(int r, int k) { return r * 64  + (k ^ ((r & 7) << 3)); } // 64-col

struct __align__(16) SMem {
  unsigned short VA[64 * 128];  // V bf16 [64][128] (dot A); reused as VT [128][64] (bt B)
  unsigned short Sb[64 * 128];  // S bf16 [64][128] (dot B / Gram A+B)
  unsigned short Gb[64 * 64];   // Gram(S) bf16 (quad B; symmetric)
  unsigned short Eb[64 * 64];   // E[n][m] bf16 (quad A)
  unsigned short ET[64 * 64];   // E^T[m][n] bf16 (bt A)
  float ns_l[64], nv_l[64];
  float csum[64], ssnum[64];
  float red_es[2][64], red_sv[2][64];   // row-sum partials (esum, svr)
  float red_p[8][32], red_s[8][32];     // col-sum partials (psum, ssp)
  float qfp[8][16];                     // quad-form partials; reused for ||bt||^2 partials
};

extern "C" __global__ void __launch_bounds__(512, 4)
mv_mfma2(const float* __restrict__ Vg, const float* __restrict__ Sg,
         float* __restrict__ out)
{
  extern __shared__ char smraw[];
  SMem& sm = *reinterpret_cast<SMem*>(smraw);

  const int t    = threadIdx.x;
  const int lane = t & 63;
  const int w    = t >> 6;
  const int l15  = lane & 15;
  const int g    = lane >> 4;          // 0..3
  const int bi   = blockIdx.x >> 5;
  const int bj   = blockIdx.x & 31;

  const float* Vi = Vg + (size_t)bi * NN * DD;
  const float* Sj = Sg + (size_t)bj * MM * DD;

  const int nb  = w >> 1;              // 16-row block (output-row side)
  const int hf  = w & 1;               // column half
  const int cB0 = hf * 32 + l15;       // B-frag col, tile 0
  const int cB1 = cB0 + 16;            // B-frag col, tile 1

  // ---- stage S (bf16, swizzled) + ns; init accumulators ----
  #pragma unroll
  for (int k = 0; k < 4; ++k) {
    const int f = t + 512 * k;         // 2048 float4s
    const int m = f >> 5, c = f & 31;
    const float4 v = reinterpret_cast<const float4*>(Sj)[f];
    u4v pk = { f2b(v.x), f2b(v.y), f2b(v.z), f2b(v.w) };
    *reinterpret_cast<u4v*>(&sm.Sb[idxV(m, c * 4)]) = pk;
    float s = v.x * v.x + v.y * v.y + v.z * v.z + v.w * v.w;
    #pragma unroll
    for (int msk = 16; msk >= 1; msk >>= 1) s += __shfl_xor(s, msk, 64);
    if ((lane & 31) == 0) sm.ns_l[m] = sqrtf(s);
  }
  if (t < 64) { sm.csum[t] = 0.f; sm.ssnum[t] = 0.f; }
  __syncthreads();

  // ---- Gram(S) via MFMA ----
  {
    f4v g0 = {0.f, 0.f, 0.f, 0.f}, g1 = {0.f, 0.f, 0.f, 0.f};
    #pragma unroll
    for (int ks = 0; ks < 4; ++ks) {
      s8v a  = *reinterpret_cast<const s8v*>(&sm.Sb[idxV(nb * 16 + l15, ks * 32 + g * 8)]);
      s8v b0 = *reinterpret_cast<const s8v*>(&sm.Sb[idxV(cB0,          ks * 32 + g * 8)]);
      s8v b1 = *reinterpret_cast<const s8v*>(&sm.Sb[idxV(cB1,          ks * 32 + g * 8)]);
      g0 = MFMA(a, b0, g0);
      g1 = MFMA(a, b1, g1);
    }
    #pragma unroll
    for (int q = 0; q < 4; ++q) {
      const int row = nb * 16 + g * 4 + q;
      sm.Gb[idx64(row, cB0)] = f2b(g0[q]);
      sm.Gb[idx64(row, cB1)] = f2b(g1[q]);
    }
  }
  // Gb first read in quad phase of tile 0 (>=3 barriers later) — no barrier needed here.

  f4v bt4[4] = {{0.f,0.f,0.f,0.f},{0.f,0.f,0.f,0.f},{0.f,0.f,0.f,0.f},{0.f,0.f,0.f,0.f}};
  float svacc = 0.f;

  for (int tt = 0; tt < NTILES; ++tt) {
    __syncthreads();                   // prev-tile bt readers of VA/ET done
    const float* Vc = Vi + (size_t)tt * TILE * DD;

    // ---- stage V tile (bf16 swizzled) + row norms ----
    #pragma unroll
    for (int k = 0; k < 4; ++k) {
      const int f = t + 512 * k;
      const int n = f >> 5, c = f & 31;
      const float4 v = reinterpret_cast<const float4*>(Vc)[f];
      u4v pk = { f2b(v.x), f2b(v.y), f2b(v.z), f2b(v.w) };
      *reinterpret_cast<u4v*>(&sm.VA[idxV(n, c * 4)]) = pk;
      float s = v.x * v.x + v.y * v.y + v.z * v.z + v.w * v.w;
      #pragma unroll
      for (int msk = 16; msk >= 1; msk >>= 1) s += __shfl_xor(s, msk, 64);
      if ((lane & 31) == 0) sm.nv_l[n] = sqrtf(s);
    }
    __syncthreads();

    // ---- dot MFMA + fixed-max weights, all in registers ----
    f4v a0 = {0.f,0.f,0.f,0.f}, a1 = {0.f,0.f,0.f,0.f};
    {
      const int ar = nb * 16 + l15;
      #pragma unroll
      for (int ks = 0; ks < 4; ++ks) {
        s8v av = *reinterpret_cast<const s8v*>(&sm.VA[idxV(ar,  ks * 32 + g * 8)]);
        s8v b0 = *reinterpret_cast<const s8v*>(&sm.Sb[idxV(cB0, ks * 32 + g * 8)]);
        s8v b1 = *reinterpret_cast<const s8v*>(&sm.Sb[idxV(cB1, ks * 32 + g * 8)]);
        a0 = MFMA(av, b0, a0);
        a1 = MFMA(av, b1, a1);
      }
    }
    float e0[4], e1[4];
    {
      const float ns0 = sm.ns_l[cB0], ns1 = sm.ns_l[cB1];
      float es[4], sv[4];
      float ps0 = 0.f, ps1 = 0.f, ss0 = 0.f, ss1 = 0.f;
      unsigned short eb0[4], eb1[4];
      #pragma unroll
      for (int q = 0; q < 4; ++q) {
        const int row = nb * 16 + g * 4 + q;
        const float nv_ = sm.nv_l[row];
        // c = a/(nv*ns+EPS); e = exp(c)  (c in [-1,1]: no max-shift needed, shift-invariant)
        e0[q] = __expf(__fdividef(a0[q], nv_ * ns0 + EPSF));
        e1[q] = __expf(__fdividef(a1[q], nv_ * ns1 + EPSF));
        const float w0 = e0[q] * a0[q], w1 = e1[q] * a1[q];   // e * rawdot (rawdot == a!)
        es[q] = e0[q] + e1[q];
        sv[q] = w0 + w1;
        ps0 += e0[q]; ps1 += e1[q]; ss0 += w0; ss1 += w1;
        eb0[q] = f2b(e0[q]); eb1[q] = f2b(e1[q]);
        sm.Eb[idx64(row, cB0)] = eb0[q];
        sm.Eb[idx64(row, cB1)] = eb1[q];
      }
      // E^T packed: rows cB0/cB1, 4 contiguous n (swizzle-safe: 4-aligned within 8-block)
      u4v et0 = { eb0[0], eb0[1], eb0[2], eb0[3] };
      u4v et1 = { eb1[0], eb1[1], eb1[2], eb1[3] };
      *reinterpret_cast<u4v*>(&sm.ET[idx64(cB0, nb * 16 + g * 4)]) = et0;
      *reinterpret_cast<u4v*>(&sm.ET[idx64(cB1, nb * 16 + g * 4)]) = et1;
      // row sums (over m): reduce across l15
      #pragma unroll
      for (int msk = 1; msk <= 8; msk <<= 1) {
        #pragma unroll
        for (int q = 0; q < 4; ++q) {
          es[q] += __shfl_xor(es[q], msk, 64);
          sv[q] += __shfl_xor(sv[q], msk, 64);
        }
      }
      if (l15 == 0) {
        #pragma unroll
        for (int q = 0; q < 4; ++q) {
          sm.red_es[hf][nb * 16 + g * 4 + q] = es[q];
          sm.red_sv[hf][nb * 16 + g * 4 + q] = sv[q];
        }
      }
      // col sums (over n): reduce across g
      #pragma unroll
      for (int msk = 16; msk <= 32; msk <<= 1) {
        ps0 += __shfl_xor(ps0, msk, 64);
        ps1 += __shfl_xor(ps1, msk, 64);
        ss0 += __shfl_xor(ss0, msk, 64);
        ss1 += __shfl_xor(ss1, msk, 64);
      }
      if (g == 0) {
        sm.red_p[w][l15]      = ps0;
        sm.red_p[w][16 + l15] = ps1;
        sm.red_s[w][l15]      = ss0;
        sm.red_s[w][16 + l15] = ss1;
      }
    }
    __syncthreads();

    // ---- quad form F = E.G via MFMA (qf = e^T G e) + VT staging overlap ----
    {
      f4v fa0 = {0.f,0.f,0.f,0.f}, fa1 = {0.f,0.f,0.f,0.f};
      #pragma unroll
      for (int ks = 0; ks < 2; ++ks) {
        s8v ea  = *reinterpret_cast<const s8v*>(&sm.Eb[idx64(nb * 16 + l15, ks * 32 + g * 8)]);
        s8v gb0 = *reinterpret_cast<const s8v*>(&sm.Gb[idx64(cB0,           ks * 32 + g * 8)]);
        s8v gb1 = *reinterpret_cast<const s8v*>(&sm.Gb[idx64(cB1,           ks * 32 + g * 8)]);
        fa0 = MFMA(ea, gb0, fa0);
        fa1 = MFMA(ea, gb1, fa1);
      }
      float qp[4];
      #pragma unroll
      for (int q = 0; q < 4; ++q) qp[q] = e0[q] * fa0[q] + e1[q] * fa1[q];  // e from regs
      #pragma unroll
      for (int msk = 1; msk <= 8; msk <<= 1) {
        #pragma unroll
        for (int q = 0; q < 4; ++q) qp[q] += __shfl_xor(qp[q], msk, 64);
      }
      if (l15 == 0) {
        #pragma unroll
        for (int q = 0; q < 4; ++q) sm.qfp[w][g * 4 + q] = qp[q];
      }
      // V^T bf16 into VA (V-layout dead after dot)
      const int d   = hf * 64 + lane;
      const int n0v = nb * 16;
      float vv[16];
      #pragma unroll
      for (int q = 0; q < 16; ++q) vv[q] = Vc[(size_t)(n0v + q) * DD + d];  // coalesced
      u8v p0, p1;
      #pragma unroll
      for (int q = 0; q < 8; ++q) { p0[q] = f2b(vv[q]); p1[q] = f2b(vv[q + 8]); }
      *reinterpret_cast<u8v*>(&sm.VA[idx64(d, n0v)])     = p0;
      *reinterpret_cast<u8v*>(&sm.VA[idx64(d, n0v + 8)]) = p1;
    }
    __syncthreads();

    // ---- bt += E^T.V via MFMA (no rescale) + wave-0 bookkeeping ----
    {
      const int db0  = hf * 4;
      const int arow = nb * 16 + l15;
      #pragma unroll
      for (int ks = 0; ks < 2; ++ks) {
        s8v pa = *reinterpret_cast<const s8v*>(&sm.ET[idx64(arow, ks * 32 + g * 8)]);
        #pragma unroll
        for (int dt = 0; dt < 4; ++dt) {
          s8v vb = *reinterpret_cast<const s8v*>(&sm.VA[idx64((db0 + dt) * 16 + l15, ks * 32 + g * 8)]);
          bt4[dt] = MFMA(pa, vb, bt4[dt]);
        }
      }
    }
    if (t < 64) {
      const float qf   = sm.qfp[2 * (t >> 4)][t & 15] + sm.qfp[2 * (t >> 4) + 1][t & 15];
      const float esum = sm.red_es[0][t] + sm.red_es[1][t];
      const float svr  = sm.red_sv[0][t] + sm.red_sv[1][t];
      svacc += svr / (sm.nv_l[t] * sqrtf(qf) + EPSF * esum);
      const int hh = t >> 5, cc = t & 31;
      float s1 = 0.f, s2 = 0.f;
      #pragma unroll
      for (int q = 0; q < 4; ++q) {
        s1 += sm.red_p[2 * q + hh][cc];
        s2 += sm.red_s[2 * q + hh][cc];
      }
      sm.csum[t] += s1;
      sm.ssnum[t] += s2;
    }
  }

  // ---- epilogue: ||bt||^2 per m, final scores ----
  __syncthreads();
  {
    float bq[4];
    #pragma unroll
    for (int q = 0; q < 4; ++q)
      bq[q] = bt4[0][q] * bt4[0][q] + bt4[1][q] * bt4[1][q]
            + bt4[2][q] * bt4[2][q] + bt4[3][q] * bt4[3][q];
    #pragma unroll
    for (int msk = 1; msk <= 8; msk <<= 1) {
      #pragma unroll
      for (int q = 0; q < 4; ++q) bq[q] += __shfl_xor(bq[q], msk, 64);
    }
    if (l15 == 0) {
      #pragma unroll
      for (int q = 0; q < 4; ++q) sm.qfp[w][g * 4 + q] = bq[q];
    }
  }
  __syncthreads();
  if (w == 0) {
    const int m = lane;
    const float btq = sm.qfp[2 * (m >> 4)][m & 15] + sm.qfp[2 * (m >> 4) + 1][m & 15];
    float ssv = sm.ssnum[m] / (sm.ns_l[m] * sqrtf(btq) + EPSF * sm.csum[m]);
    float svv = svacc;
    #pragma unroll
    for (int msk = 32; msk >= 1; msk >>= 1) {
      ssv += __shfl_xor(ssv, msk, 64);
      svv += __shfl_xor(svv, msk, 64);
    }
    if (lane == 0) {
      out[bi * BB + bj]           = svv * (1.0f / NN);
      out[BB * BB + bj * BB + bi] = ssv * (1.0f / MM);  // transposed output
    }
  }
}

extern "C" void kernel_launch(void* const* d_in, const int* in_sizes, int n_in,
                              void* d_out, int out_size, void* d_ws, size_t ws_size,
                              hipStream_t stream) {
  const float* V = (const float*)d_in[0];   // [32, 512, 128] f32
  const float* S = (const float*)d_in[1];   // [32, 64, 128] f32
  float* out = (float*)d_out;               // [2048] f32

  static_assert(sizeof(SMem) <= 80 * 1024, "need 2 blocks/CU");
  hipFuncSetAttribute(reinterpret_cast<const void*>(mv_mfma2),
                      hipFuncAttributeMaxDynamicSharedMemorySize,
                      (int)sizeof(SMem));
  mv_mfma2<<<dim3(BB * BB), dim3(512), sizeof(SMem), stream>>>(V, S, out);
}